// Round 5
// baseline (54.966 us; speedup 1.0000x reference)
//
#include <hip/hip_runtime.h>

// Problem constants: B=4, S=2000, F=128, NGRAMS=5, G=400, H=5, K=2
#define BB 4
#define SS 2000
#define FF 128
#define NG 5
#define GG 400
#define HH 5

#define LOG2E   1.4426950408889634f
#define RSQRT2  0.70710678118654752f

#if defined(__has_builtin)
#if __has_builtin(__builtin_amdgcn_exp2f)
#define EXP2F(x) __builtin_amdgcn_exp2f(x)
#else
#define EXP2F(x) exp2f(x)
#endif
#else
#define EXP2F(x) exp2f(x)
#endif

// ob scratch: [B][G][H][K][F] floats
#define OB_BYTES ((size_t)BB * GG * HH * 2 * FF * 4)

__device__ __forceinline__ float bcast(float v, int lane) {
    return __int_as_float(__builtin_amdgcn_readlane(__float_as_int(v), lane));
}

// ---------------- Kernel 1: per-head attention ----------------
// 2000 blocks x 256 threads = 8000 waves; wave = one (b,g,h) task.
// No LDS, no barriers: waves fully independent -> max residency (8/SIMD).
// Main loop is register-only with v_readlane broadcast of k/v per key token.
__global__ __launch_bounds__(256) void attn_heads_kernel(
    const float* __restrict__ x,
    const float* __restrict__ Wq, const float* __restrict__ bq,
    const float* __restrict__ Wk, const float* __restrict__ bk,
    const float* __restrict__ Wv, const float* __restrict__ bv,
    float* __restrict__ ob)   // [B][G][H][K][F]
{
    const int l = threadIdx.x & 63;
    // wave-uniform task id (forced scalar)
    const int w   = __builtin_amdgcn_readfirstlane((int)blockIdx.x * 4 + ((int)threadIdx.x >> 6));
    const int b   = w / (GG * HH);
    const int rem = w - b * (GG * HH);
    const int g   = rem / HH;
    const int h   = rem - g * HH;

    // ---- per-wave weights (wave-uniform -> scalar loads) ----
    float wqh[10], wkh[10], wvh[10];
    #pragma unroll
    for (int n = 0; n < NG; ++n) {
        #pragma unroll
        for (int k = 0; k < 2; ++k) {
            const int wi = g*50 + (n*HH + h)*2 + k;
            wqh[n*2 + k] = Wq[wi];
            wkh[n*2 + k] = Wk[wi];
            wvh[n*2 + k] = Wv[wi];
        }
    }
    const float bq0 = bq[(g*HH + h)*2 + 0], bq1 = bq[(g*HH + h)*2 + 1];
    const float bk0 = bk[(g*HH + h)*2 + 0], bk1 = bk[(g*HH + h)*2 + 1];
    const float bv0 = bv[(g*HH + h)*2 + 0], bv1 = bv[(g*HH + h)*2 + 1];

    // ---- x loads: lane l -> x[b, g*5+n, l] and [.., l+64] (coalesced) ----
    const float* xp = x + ((size_t)b * SS + (size_t)g * NG) * FF;
    float xa[NG], xb[NG];
    #pragma unroll
    for (int n = 0; n < NG; ++n) {
        xa[n] = xp[n * FF + l];
        xb[n] = xp[n * FF + l + 64];
    }

    // ---- q/k/v projection: tokens l (a) and l+64 (b) ----
    float qa0 = bq0, qa1 = bq1, ka0 = bk0, ka1 = bk1, va0 = bv0, va1 = bv1;
    float qb0 = bq0, qb1 = bq1, kb0 = bk0, kb1 = bk1, vb0 = bv0, vb1 = bv1;
    #pragma unroll
    for (int n = 0; n < NG; ++n) {
        const float a = xa[n], c = xb[n];
        qa0 = fmaf(a, wqh[n*2+0], qa0);  qa1 = fmaf(a, wqh[n*2+1], qa1);
        ka0 = fmaf(a, wkh[n*2+0], ka0);  ka1 = fmaf(a, wkh[n*2+1], ka1);
        va0 = fmaf(a, wvh[n*2+0], va0);  va1 = fmaf(a, wvh[n*2+1], va1);
        qb0 = fmaf(c, wqh[n*2+0], qb0);  qb1 = fmaf(c, wqh[n*2+1], qb1);
        kb0 = fmaf(c, wkh[n*2+0], kb0);  kb1 = fmaf(c, wkh[n*2+1], kb1);
        vb0 = fmaf(c, wvh[n*2+0], vb0);  vb1 = fmaf(c, wvh[n*2+1], vb1);
    }
    // fold score scale (1/sqrt(2)) + log2(e) into q -> softmax is a bare exp2
    const float cs = RSQRT2 * LOG2E;
    qa0 *= cs; qa1 *= cs; qb0 *= cs; qb1 *= cs;

    // ---- main loop: register-only; softmax shift skipped (scores ~ O(0.1)) ----
    float s0 = 0.f, s1 = 0.f;
    float o00 = 0.f, o01 = 0.f, o10 = 0.f, o11 = 0.f;
    #pragma unroll
    for (int t = 0; t < FF; ++t) {
        const int lane = t & 63;
        float k0, k1, v0, v1;
        if (t < 64) {
            k0 = bcast(ka0, lane); k1 = bcast(ka1, lane);
            v0 = bcast(va0, lane); v1 = bcast(va1, lane);
        } else {
            k0 = bcast(kb0, lane); k1 = bcast(kb1, lane);
            v0 = bcast(vb0, lane); v1 = bcast(vb1, lane);
        }
        const float sa = fmaf(qa1, k1, qa0 * k0);
        const float sb = fmaf(qb1, k1, qb0 * k0);
        const float pa = EXP2F(sa);
        const float pb = EXP2F(sb);
        s0 += pa;  s1 += pb;
        o00 = fmaf(pa, v0, o00);  o01 = fmaf(pa, v1, o01);
        o10 = fmaf(pb, v0, o10);  o11 = fmaf(pb, v1, o11);
    }
    const float r0 = 1.0f / s0;
    const float r1 = 1.0f / s1;

    // ---- store normalized per-head output, coalesced (4 x 256B wave stores) ----
    float* obp = ob + (((size_t)(b*GG + g) * HH + h) * 2) * FF;
    obp[l]            = o00 * r0;   // k=0, f=l
    obp[FF + l]       = o01 * r0;   // k=1, f=l
    obp[l + 64]       = o10 * r1;   // k=0, f=l+64
    obp[FF + l + 64]  = o11 * r1;   // k=1, f=l+64
}

// ---------------- Kernel 2: output projection ----------------
// Block = (b,g): stage 5KB ob slice + Wo in LDS, 10 FMA per output element.
__global__ __launch_bounds__(256) void proj_kernel(
    const float* __restrict__ ob, const float* __restrict__ Wo,
    const float* __restrict__ bo, float* __restrict__ out)
{
    const int g   = blockIdx.x;
    const int b   = blockIdx.y;
    const int tid = threadIdx.x;

    __shared__ float obs[HH * 2 * FF];   // 1280 floats
    __shared__ float wos[50], bos[5];

    const float* obp = ob + (size_t)(b*GG + g) * (HH * 2 * FF);
    #pragma unroll
    for (int i = tid; i < HH * 2 * FF; i += 256) obs[i] = obp[i];
    if      (tid < 50) wos[tid]      = Wo[g*50 + tid];
    else if (tid < 55) bos[tid - 50] = bo[g*5 + (tid - 50)];
    __syncthreads();

    // 640 outputs: out[b,f,n,g] -> d_out[b*256000 + f*2000 + n*400 + g]
    for (int oi = tid; oi < FF * NG; oi += 256) {
        const int f = oi / 5;
        const int n = oi - f * 5;
        float acc = bos[n];
        #pragma unroll
        for (int hh = 0; hh < HH; ++hh) {
            #pragma unroll
            for (int kk = 0; kk < 2; ++kk)
                acc = fmaf(obs[(hh*2 + kk)*FF + f], wos[hh*10 + kk*5 + n], acc);
        }
        out[(size_t)b * (SS * FF) + (size_t)f * 2000 + n * 400 + g] = acc;
    }
}

// ---------------- Fallback: R4 monolithic kernel (if ws too small) ----------------
__global__ __launch_bounds__(320) void ngram_mha_kernel(
    const float* __restrict__ x,
    const float* __restrict__ Wq, const float* __restrict__ bq,
    const float* __restrict__ Wk, const float* __restrict__ bk,
    const float* __restrict__ Wv, const float* __restrict__ bv,
    const float* __restrict__ Wo, const float* __restrict__ bo,
    float* __restrict__ out)
{
    const int g   = blockIdx.x;
    const int b   = blockIdx.y;
    const int tid = threadIdx.x;
    const int h   = __builtin_amdgcn_readfirstlane(tid >> 6);
    const int l   = tid & 63;

    __shared__ float  wo[50];
    __shared__ float  bos[5];
    __shared__ float2 obl[FF * HH];

    if      (tid < 50) wo[tid]       = Wo[g*50 + tid];
    else if (tid < 55) bos[tid - 50] = bo[g*5 + (tid - 50)];

    float wqh[10], wkh[10], wvh[10];
    #pragma unroll
    for (int n = 0; n < NG; ++n)
        #pragma unroll
        for (int k = 0; k < 2; ++k) {
            const int wi = g*50 + (n*HH + h)*2 + k;
            wqh[n*2+k] = Wq[wi]; wkh[n*2+k] = Wk[wi]; wvh[n*2+k] = Wv[wi];
        }
    const float bq0 = bq[(g*HH+h)*2+0], bq1 = bq[(g*HH+h)*2+1];
    const float bk0 = bk[(g*HH+h)*2+0], bk1 = bk[(g*HH+h)*2+1];
    const float bv0 = bv[(g*HH+h)*2+0], bv1 = bv[(g*HH+h)*2+1];

    const float* xp = x + ((size_t)b * SS + (size_t)g * NG) * FF;
    float xa[NG], xb[NG];
    #pragma unroll
    for (int n = 0; n < NG; ++n) { xa[n] = xp[n*FF + l]; xb[n] = xp[n*FF + l + 64]; }

    float qa0=bq0,qa1=bq1,ka0=bk0,ka1=bk1,va0=bv0,va1=bv1;
    float qb0=bq0,qb1=bq1,kb0=bk0,kb1=bk1,vb0=bv0,vb1=bv1;
    #pragma unroll
    for (int n = 0; n < NG; ++n) {
        const float a = xa[n], c = xb[n];
        qa0=fmaf(a,wqh[n*2+0],qa0); qa1=fmaf(a,wqh[n*2+1],qa1);
        ka0=fmaf(a,wkh[n*2+0],ka0); ka1=fmaf(a,wkh[n*2+1],ka1);
        va0=fmaf(a,wvh[n*2+0],va0); va1=fmaf(a,wvh[n*2+1],va1);
        qb0=fmaf(c,wqh[n*2+0],qb0); qb1=fmaf(c,wqh[n*2+1],qb1);
        kb0=fmaf(c,wkh[n*2+0],kb0); kb1=fmaf(c,wkh[n*2+1],kb1);
        vb0=fmaf(c,wvh[n*2+0],vb0); vb1=fmaf(c,wvh[n*2+1],vb1);
    }
    const float cs = RSQRT2 * LOG2E;
    qa0*=cs; qa1*=cs; qb0*=cs; qb1*=cs;

    float s0=0.f,s1=0.f,o00=0.f,o01=0.f,o10=0.f,o11=0.f;
    #pragma unroll
    for (int t = 0; t < FF; ++t) {
        const int lane = t & 63;
        float k0,k1,v0,v1;
        if (t < 64) { k0=bcast(ka0,lane); k1=bcast(ka1,lane); v0=bcast(va0,lane); v1=bcast(va1,lane); }
        else        { k0=bcast(kb0,lane); k1=bcast(kb1,lane); v0=bcast(vb0,lane); v1=bcast(vb1,lane); }
        const float sa = fmaf(qa1,k1,qa0*k0);
        const float sb = fmaf(qb1,k1,qb0*k0);
        const float pa = EXP2F(sa); const float pb = EXP2F(sb);
        s0 += pa; s1 += pb;
        o00 = fmaf(pa,v0,o00); o01 = fmaf(pa,v1,o01);
        o10 = fmaf(pb,v0,o10); o11 = fmaf(pb,v1,o11);
    }
    const float r0 = 1.0f/s0, r1 = 1.0f/s1;
    obl[l*HH + h]        = make_float2(o00*r0, o01*r0);
    obl[(l+64)*HH + h]   = make_float2(o10*r1, o11*r1);
    __syncthreads();

    for (int oi = tid; oi < FF*NG; oi += 320) {
        const int f = oi/5, n = oi - (oi/5)*5;
        float acc = bos[n];
        #pragma unroll
        for (int hh = 0; hh < HH; ++hh) {
            const float2 o2 = obl[f*5 + hh];
            acc = fmaf(o2.x, wo[(hh*2+0)*5 + n], acc);
            acc = fmaf(o2.y, wo[(hh*2+1)*5 + n], acc);
        }
        out[(size_t)b*(SS*FF) + (size_t)f*2000 + n*400 + g] = acc;
    }
}

extern "C" void kernel_launch(void* const* d_in, const int* in_sizes, int n_in,
                              void* d_out, int out_size, void* d_ws, size_t ws_size,
                              hipStream_t stream) {
    const float* x  = (const float*)d_in[0];
    const float* Wq = (const float*)d_in[1];
    const float* bq = (const float*)d_in[2];
    const float* Wk = (const float*)d_in[3];
    const float* bk = (const float*)d_in[4];
    const float* Wv = (const float*)d_in[5];
    const float* bv = (const float*)d_in[6];
    const float* Wo = (const float*)d_in[7];
    const float* bo = (const float*)d_in[8];
    float* out = (float*)d_out;

    if (ws_size >= OB_BYTES) {
        float* ob = (float*)d_ws;
        attn_heads_kernel<<<(BB*GG*HH)/4, 256, 0, stream>>>(x, Wq, bq, Wk, bk, Wv, bv, ob);
        proj_kernel<<<dim3(GG, BB), 256, 0, stream>>>(ob, Wo, bo, out);
    } else {
        ngram_mha_kernel<<<dim3(GG, BB), 320, 0, stream>>>(x, Wq, bq, Wk, bk, Wv, bv, Wo, bo, out);
    }
}

// Round 6
// 38.484 us; speedup vs baseline: 1.4283x; 1.4283x over previous
//
#include <hip/hip_runtime.h>

// Problem constants: B=4, S=2000, F=128, NGRAMS=5, G=400, H=5, K=2
#define BB 4
#define SS 2000
#define FF 128
#define NG 5
#define GG 400
#define HH 5

#define LOG2E   1.4426950408889634f
#define RSQRT2  0.70710678118654752f

#if defined(__has_builtin)
#if __has_builtin(__builtin_amdgcn_exp2f)
#define EXP2F(x) __builtin_amdgcn_exp2f(x)
#else
#define EXP2F(x) exp2f(x)
#endif
#else
#define EXP2F(x) exp2f(x)
#endif

// One block per (b,g): 320 threads = 5 waves, wave = head h, lane l = tokens {l, l+64}.
// kv staged ONCE in LDS [t][h] float4; main loop = 1 broadcast ds_read_b128 + ~10 VALU
// + 2 exp2 per token, unrolled x8 (small I$ footprint, low VGPR -> 8 waves/SIMD).
__global__ __launch_bounds__(320, 8) void ngram_mha_kernel(
    const float* __restrict__ x,
    const float* __restrict__ Wq, const float* __restrict__ bq,
    const float* __restrict__ Wk, const float* __restrict__ bk,
    const float* __restrict__ Wv, const float* __restrict__ bv,
    const float* __restrict__ Wo, const float* __restrict__ bo,
    float* __restrict__ out)
{
    const int g   = blockIdx.x;   // 0..399
    const int b   = blockIdx.y;   // 0..3
    const int tid = threadIdx.x;  // 0..319
    const int h   = __builtin_amdgcn_readfirstlane(tid >> 6);  // wave = head
    const int l   = tid & 63;

    __shared__ float4 kv[FF * HH];    // [t][h] = (k0,k1,v0,v1)   10.24 KB
    __shared__ float2 ob[FF * HH];    // [f][h] = (o0,o1)/sum      5.12 KB
    __shared__ float  wo[50], bos[5];

    if      (tid < 50) wo[tid]       = Wo[g*50 + tid];
    else if (tid < 55) bos[tid - 50] = bo[g*5 + (tid - 50)];

    // ---- per-wave (wave-uniform -> SGPR) weights for this head ----
    float wqh[10], wkh[10], wvh[10];
    #pragma unroll
    for (int n = 0; n < NG; ++n) {
        #pragma unroll
        for (int k = 0; k < 2; ++k) {
            const int wi = g*50 + (n*HH + h)*2 + k;
            wqh[n*2 + k] = Wq[wi];
            wkh[n*2 + k] = Wk[wi];
            wvh[n*2 + k] = Wv[wi];
        }
    }
    const float bq0 = bq[(g*HH + h)*2 + 0], bq1 = bq[(g*HH + h)*2 + 1];
    const float bk0 = bk[(g*HH + h)*2 + 0], bk1 = bk[(g*HH + h)*2 + 1];
    const float bv0 = bv[(g*HH + h)*2 + 0], bv1 = bv[(g*HH + h)*2 + 1];

    // ---- x loads: lane l -> x[b, g*5+n, l] and [.., l+64] (coalesced) ----
    const float* xp = x + ((size_t)b * SS + (size_t)g * NG) * FF;
    float xa[NG], xb[NG];
    #pragma unroll
    for (int n = 0; n < NG; ++n) {
        xa[n] = xp[n * FF + l];
        xb[n] = xp[n * FF + l + 64];
    }

    // ---- q/k/v projection for this head, tokens l (a) and l+64 (b) ----
    float qa0 = bq0, qa1 = bq1, ka0 = bk0, ka1 = bk1, va0 = bv0, va1 = bv1;
    float qb0 = bq0, qb1 = bq1, kb0 = bk0, kb1 = bk1, vb0 = bv0, vb1 = bv1;
    #pragma unroll
    for (int n = 0; n < NG; ++n) {
        const float a = xa[n], c = xb[n];
        qa0 = fmaf(a, wqh[n*2+0], qa0);  qa1 = fmaf(a, wqh[n*2+1], qa1);
        ka0 = fmaf(a, wkh[n*2+0], ka0);  ka1 = fmaf(a, wkh[n*2+1], ka1);
        va0 = fmaf(a, wvh[n*2+0], va0);  va1 = fmaf(a, wvh[n*2+1], va1);
        qb0 = fmaf(c, wqh[n*2+0], qb0);  qb1 = fmaf(c, wqh[n*2+1], qb1);
        kb0 = fmaf(c, wkh[n*2+0], kb0);  kb1 = fmaf(c, wkh[n*2+1], kb1);
        vb0 = fmaf(c, wvh[n*2+0], vb0);  vb1 = fmaf(c, wvh[n*2+1], vb1);
    }
    // stage k/v for both tokens (this wave's head column)
    kv[l        * HH + h] = make_float4(ka0, ka1, va0, va1);
    kv[(l + 64) * HH + h] = make_float4(kb0, kb1, vb0, vb1);

    // fold score scale (1/sqrt(2)) + log2(e) into q -> softmax is a bare exp2;
    // shift-free softmax is exact enough here (scores ~ O(0.05)).
    const float cs = RSQRT2 * LOG2E;
    const float2 qx = make_float2(qa0 * cs, qb0 * cs);   // (a,b) pair, k-dim 0
    const float2 qy = make_float2(qa1 * cs, qb1 * cs);   // (a,b) pair, k-dim 1
    __syncthreads();

    // ---- main loop: 1 broadcast ds_read_b128 + packed f32 math per token ----
    float2 ssum = make_float2(0.f, 0.f);
    float2 o0   = make_float2(0.f, 0.f);
    float2 o1   = make_float2(0.f, 0.f);
    const float4* __restrict__ kvh = kv + h;   // wave-uniform address stream

    #pragma unroll 8
    for (int t = 0; t < FF; ++t) {
        const float4 e = kvh[t * HH];
        float2 s2;
        s2.x = fmaf(qy.x, e.y, qx.x * e.x);
        s2.y = fmaf(qy.y, e.y, qx.y * e.x);
        float2 p;
        p.x = EXP2F(s2.x);
        p.y = EXP2F(s2.y);
        ssum.x += p.x;               ssum.y += p.y;
        o0.x = fmaf(p.x, e.z, o0.x); o0.y = fmaf(p.y, e.z, o0.y);
        o1.x = fmaf(p.x, e.w, o1.x); o1.y = fmaf(p.y, e.w, o1.y);
    }
    const float r0 = 1.0f / ssum.x;
    const float r1 = 1.0f / ssum.y;
    ob[l        * HH + h] = make_float2(o0.x * r0, o1.x * r0);
    ob[(l + 64) * HH + h] = make_float2(o0.y * r1, o1.y * r1);
    __syncthreads();

    // ---- output projection + scatter: out[b,f,n,g] -> d_out[b*256000 + f*2000 + n*400 + g] ----
    for (int oi = tid; oi < FF * NG; oi += 320) {
        const int f = oi / 5;
        const int n = oi - f * 5;
        float acc = bos[n];
        #pragma unroll
        for (int hh = 0; hh < HH; ++hh) {
            const float2 o2 = ob[f*5 + hh];
            acc = fmaf(o2.x, wo[(hh*2 + 0)*5 + n], acc);
            acc = fmaf(o2.y, wo[(hh*2 + 1)*5 + n], acc);
        }
        out[(size_t)b * (SS * FF) + (size_t)f * 2000 + n * 400 + g] = acc;
    }
}

extern "C" void kernel_launch(void* const* d_in, const int* in_sizes, int n_in,
                              void* d_out, int out_size, void* d_ws, size_t ws_size,
                              hipStream_t stream) {
    const float* x  = (const float*)d_in[0];
    const float* Wq = (const float*)d_in[1];
    const float* bq = (const float*)d_in[2];
    const float* Wk = (const float*)d_in[3];
    const float* bk = (const float*)d_in[4];
    const float* Wv = (const float*)d_in[5];
    const float* bv = (const float*)d_in[6];
    const float* Wo = (const float*)d_in[7];
    const float* bo = (const float*)d_in[8];
    float* out = (float*)d_out;

    dim3 grid(GG, BB);   // 1600 blocks, one per (b,g)
    ngram_mha_kernel<<<grid, 320, 0, stream>>>(x, Wq, bq, Wk, bk, Wv, bv, Wo, bo, out);
}